// Round 22
// baseline (265.303 us; speedup 1.0000x reference)
//
#include <hip/hip_runtime.h>
#include <hip/hip_bf16.h>

#define EPSV 1e-5f

// workspace layout: [wB2][xTp][stats]
#define WB2_ELEMS (2*4*36*256*32)          // [p][nt(4)][kt(36)][nl(256)][kk(32)] bf16
#define WB2_BYTES ((size_t)WB2_ELEMS*2)    // 4,718,592
#define XTP_ELEMS (8*68*68*128)            // padded channels-last x, bf16
#define XTP_BYTES ((size_t)XTP_ELEMS*2)    // 9,469,952
#define STATS_OFF (WB2_BYTES + XTP_BYTES)  // 1024 float2 partials

typedef __attribute__((ext_vector_type(8))) short short8;
typedef __attribute__((ext_vector_type(4))) float f32x4;

__device__ __forceinline__ void gload_lds16(const void* g, void* l) {
    __builtin_amdgcn_global_load_lds(
        (const __attribute__((address_space(1))) void*)g,
        (__attribute__((address_space(3))) void*)l, 16, 0, 0);
}

// ---------------------------------------------------------------------------
// x [8][128][64][64] f32  ->  xTp [8][68][68][128] bf16 (2-px zero halo)
__global__ __launch_bounds__(256) void k_xpad(const float* __restrict__ x,
                                              __hip_bfloat16* __restrict__ xTp) {
    int bh = blockIdx.x; int b = bh >> 6, h = bh & 63;
    __shared__ __hip_bfloat16 tile[64][130];
    int t = threadIdx.x;
#pragma unroll
    for (int i = 0; i < 32; ++i) {
        int e = (i << 8) + t; int w = e & 63; int ci = e >> 6;
        tile[w][ci] = __float2bfloat16(x[(((size_t)(b*128 + ci))*64 + h)*64 + w]);
    }
    __syncthreads();
    __hip_bfloat16* dst = xTp + ((size_t)((b*68 + h + 2)*68 + 2))*128;
#pragma unroll
    for (int i = 0; i < 32; ++i) {
        int e = (i << 8) + t; int ci = e & 127; int w = e >> 7;
        dst[w*128 + ci] = tile[w][ci];
    }
}

// ---------------------------------------------------------------------------
// w_mid [128][16][128][3][3] f32 -> wB2 [p][nt(4)][kt(36)][nl(256)][kk(32)]
__global__ void k_wrepack(const float* __restrict__ w_mid,
                          __hip_bfloat16* __restrict__ wB2) {
    int idx = blockIdx.x * 256 + threadIdx.x;
    if (idx >= WB2_ELEMS) return;
    int kk  = idx & 31;
    int nl  = (idx >> 5) & 255;
    int q   = idx >> 13;             // (p*4+nt)*36 + kt
    int kt  = q % 36;
    int pnt = q / 36;                // 0..7
    int nt  = pnt & 3, p = pnt >> 2;
    int c = ((nt*16 + (nl >> 4)) << 1) + p;
    int m = nl & 15;
    int k = kt*32 + kk;
    int tap = k >> 7, ci = k & 127;
    wB2[idx] = __float2bfloat16(w_mid[((size_t)((c*16 + m)*128 + ci))*9 + tap]);
}

// ---------------------------------------------------------------------------
// Implicit-GEMM conv — R21 8-phase skeleton with B IN REGISTERS (no B LDS):
// BM=256 x BN=256, BK=32, 8 waves (2M x 4N), acc 8x4. A: 4 rotating LDS
// dbufs (64 KB static), staged 2 ktiles ahead via global_load_lds, counted
// vmcnt(6) only at ktile boundaries. B: wave-coalesced 1 KB global reads
// (L2-resident) into breg[2][4] at ktile entry, distance-1 (consumed a full
// ktile later; register scoreboard handles correctness). Cuts per-phase LDS
// fragment traffic 578 -> 289 cyc and halves staging loads vs R21.
__global__ __launch_bounds__(512, 2) void k_conv(
    const __hip_bfloat16* __restrict__ xTp,
    const __hip_bfloat16* __restrict__ wB2,
    const float* __restrict__ w_pt,
    const float* __restrict__ b_pt,
    float* __restrict__ y) {
    __shared__ __hip_bfloat16 Ae[4*8192];   // 4 dbufs x 16 KB (256 rows x 32 k)

    const int combo = blockIdx.x & 7;      // XCD: one (p, nt) each
    const int p  = combo & 1;
    const int nt = combo >> 1;             // 0..3
    const int mt = blockIdx.x >> 3;        // 0..127 (256 spatial rows each)
    const int dil = 1 + p;

    const int t = threadIdx.x;             // 0..511
    const int lane = t & 63;
    const int wave = t >> 6;               // 0..7
    const int wm = wave >> 2;              // 0..1
    const int wn = wave & 3;               // 0..3
    const int lm = lane & 15, lg = lane >> 4;

    // ---- A staging addressing (R15/R21-verbatim) ----
    const int rsub = t >> 2;                              // row 0..127
    const int ksub = (((t & 3) ^ ((t >> 3) & 3)) << 3);   // src-side swizzled slot
    const __hip_bfloat16* abase0;
    const __hip_bfloat16* abase1;
    {
        int s0 = mt*256 + rsub;
        int s1 = s0 + 128;
        abase0 = xTp + ((size_t)(((s0>>12)*68 + ((s0>>6)&63) + 2)*68 + (s0&63) + 2))*128 + ksub;
        abase1 = xTp + ((size_t)(((s1>>12)*68 + ((s1>>6)&63) + 2)*68 + (s1&63) + 2))*128 + ksub;
    }
    // B register-load base (R7/R17-proven coalesced shape): frag j of ktile kt
    // at bptr + kt*8192 + j*512  (1 KB contiguous per wave instruction)
    const __hip_bfloat16* bptr = wB2 + (size_t)(p*4 + nt)*(36*8192)
                               + (wn*64 + lm)*32 + lg*8;

    // ---- A ds-read offsets (R21-verbatim swizzle) ----
    const int sslot = (lg ^ ((lm >> 1) & 3)) << 3;
    const int aoffb = (wm*128 + lm)*32 + sslot;     // + i*512 (elems) + dbuf*8192

    f32x4 acc[8][4];
#pragma unroll
    for (int i = 0; i < 8; ++i)
#pragma unroll
        for (int j = 0; j < 4; ++j) acc[i][j] = (f32x4){0.f, 0.f, 0.f, 0.f};

    short8 breg[2][4];

    // ---- prologue: stage A(kt0)->dbuf0, A(kt1)->dbuf1; load B(kt0) regs ----
    {
        const int t0 = -dil*8832;    // tap 0: kh=-1, kw=-1; ci chunk 0
        gload_lds16(abase0 + t0,      (char*)Ae + (0*1024 + t)*16);        // kt0 h0
        gload_lds16(abase1 + t0,      (char*)Ae + (0*1024 + 512 + t)*16);  // kt0 h1
        gload_lds16(abase0 + t0 + 32, (char*)Ae + (1*1024 + t)*16);        // kt1 h0
        gload_lds16(abase1 + t0 + 32, (char*)Ae + (1*1024 + 512 + t)*16);  // kt1 h1
#pragma unroll
        for (int j = 0; j < 4; ++j)
            breg[0][j] = *(const short8*)(bptr + j*512);
    }
    asm volatile("s_waitcnt vmcnt(6)" ::: "memory");   // kt0's A resident
    __builtin_amdgcn_s_barrier();
    __builtin_amdgcn_sched_barrier(0);

    // ---- K-loop: kt = 4*vv + ss ----
#pragma unroll 1
    for (int vv = 0; vv < 9; ++vv) {
        // tap offsets for staging ktile kt+2 (taps vv and vv+1), R21-verbatim
        const int q3c = (vv*11) >> 5;
        const int toff_c = dil*128*((q3c - 1)*68 + (vv - 3*q3c - 1));
        const int vn = vv + 1;
        const int q3n = (vn*11) >> 5;
        const int toff_n = dil*128*((q3n - 1)*68 + (vn - 3*q3n - 1));
#pragma unroll
        for (int ss = 0; ss < 4; ++ss) {
            const int d  = ss;                 // A dbuf of ktile kt (static)
            const int d2 = (ss + 2) & 3;       // A dbuf staged (static)
            const bool do_stage = (vv < 8) || (ss < 2);   // kt+2 <= 35
            const bool do_bload = (vv < 8) || (ss < 3);   // kt+1 <= 35
            const int aoff = (ss < 2) ? (toff_c + (ss + 2)*32)
                                      : (toff_n + (ss - 2)*32);
            // ktile entry: B regs for kt+1 (distance-1, full-ktile cover)
            if (do_bload) {
#pragma unroll
                for (int j = 0; j < 4; ++j)
                    breg[(ss+1)&1][j] =
                        *(const short8*)(bptr + (size_t)(4*vv + ss + 1)*8192 + j*512);
            }
            short8 af[4];
#pragma unroll
            for (int q = 0; q < 2; ++q) {
                // this phase's A fragments (waited by lgkmcnt(0) after barrier)
#pragma unroll
                for (int ii = 0; ii < 4; ++ii)
                    af[ii] = *(const short8*)(Ae + d*8192 + aoffb + (q*4 + ii)*512);
                // stage half of A(kt+2)
                if (do_stage) {
                    if (q == 0) gload_lds16(abase0 + aoff, (char*)Ae + (d2*1024 + t)*16);
                    else        gload_lds16(abase1 + aoff, (char*)Ae + (d2*1024 + 512 + t)*16);
                }
                // ktile boundary: A(kt+1) must be resident (its 2 loads are the
                // oldest of at most 8 outstanding) -> vmcnt(6); drain at kt=34
                if (q == 1) {
                    if (vv == 8 && ss >= 2) asm volatile("s_waitcnt vmcnt(0)" ::: "memory");
                    else                    asm volatile("s_waitcnt vmcnt(6)" ::: "memory");
                }
                __builtin_amdgcn_s_barrier();
                asm volatile("s_waitcnt lgkmcnt(0)" ::: "memory");
                __builtin_amdgcn_sched_barrier(0);
                __builtin_amdgcn_s_setprio(1);
#pragma unroll
                for (int ii = 0; ii < 4; ++ii)
#pragma unroll
                    for (int j = 0; j < 4; ++j)
                        acc[q*4 + ii][j] = __builtin_amdgcn_mfma_f32_16x16x32_bf16(
                            af[ii], breg[ss&1][j], acc[q*4 + ii][j], 0, 0, 0);
                __builtin_amdgcn_s_setprio(0);
            }
        }
    }

    // ---- epilogue (R21-verbatim): leaky -> *w_pt -> 16-lane reduce -> +b_pt ----
#pragma unroll
    for (int j = 0; j < 4; ++j) {
        int n_g = nt*256 + wn*64 + j*16 + lm;
        int c = ((n_g >> 4) << 1) + p;     // uniform across the 16-lane group
        float wp = w_pt[c*16 + lm];        // m == lm
        float bp = b_pt[c];
#pragma unroll
        for (int i = 0; i < 8; ++i) {
#pragma unroll
            for (int r = 0; r < 4; ++r) {
                float v = acc[i][j][r];
                v = v >= 0.f ? v : 0.1f*v;
                v *= wp;
                v += __shfl_xor(v, 1);
                v += __shfl_xor(v, 2);
                v += __shfl_xor(v, 4);
                v += __shfl_xor(v, 8);
                if (lm == 0) {
                    int s = mt*256 + wm*128 + i*16 + lg*4 + r;
                    int b = s >> 12, hw = s & 4095;
                    y[(size_t)(b*128 + c)*4096 + hw] = v + bp;
                }
            }
        }
    }
}

// ---------------------------------------------------------------------------
// per-(b,c)-plane partial sums (float4 loads, no atomics, deterministic)
__global__ __launch_bounds__(256) void k_ystat(const float* __restrict__ y,
                                               float2* __restrict__ partials) {
    int P = blockIdx.x;                 // plane = b*128 + c
    const float4* base = (const float4*)(y + (size_t)P*4096);
    int t = threadIdx.x;
    float s = 0.f, s2 = 0.f;
#pragma unroll
    for (int i = 0; i < 4; ++i) {
        float4 v = base[t + i*256];
        s  += v.x + v.y + v.z + v.w;
        s2 += v.x*v.x + v.y*v.y + v.z*v.z + v.w*v.w;
    }
#pragma unroll
    for (int o = 32; o; o >>= 1) { s += __shfl_down(s, o); s2 += __shfl_down(s2, o); }
    __shared__ float ss[4], ss2[4];
    if ((t & 63) == 0) { ss[t >> 6] = s; ss2[t >> 6] = s2; }
    __syncthreads();
    if (t == 0)
        partials[P] = make_float2(ss[0]+ss[1]+ss[2]+ss[3], ss2[0]+ss2[1]+ss2[2]+ss2[3]);
}

// BN finalize + apply + ReLU. Block covers 256 float4 = quarter of one plane.
__global__ __launch_bounds__(256) void k_bn_apply(float* __restrict__ y,
                                                  const float2* __restrict__ partials,
                                                  const float* __restrict__ gamma,
                                                  const float* __restrict__ beta) {
    int bid = blockIdx.x;
    int c = (bid >> 2) & 127;
    float s = 0.f, s2 = 0.f;
#pragma unroll
    for (int b = 0; b < 8; ++b) {
        float2 pr = partials[b*128 + c];
        s += pr.x; s2 += pr.y;
    }
    float mean = s * (1.f/32768.f);
    float var  = s2 * (1.f/32768.f) - mean*mean;
    float scale = gamma[c] * rsqrtf(var + EPSV);
    float shift = beta[c] - mean*scale;
    float4* y4 = (float4*)y;
    int idx = bid*256 + threadIdx.x;
    float4 v = y4[idx];
    v.x = fmaxf(v.x*scale + shift, 0.f);
    v.y = fmaxf(v.y*scale + shift, 0.f);
    v.z = fmaxf(v.z*scale + shift, 0.f);
    v.w = fmaxf(v.w*scale + shift, 0.f);
    y4[idx] = v;
}

// ---------------------------------------------------------------------------
extern "C" void kernel_launch(void* const* d_in, const int* in_sizes, int n_in,
                              void* d_out, int out_size, void* d_ws, size_t ws_size,
                              hipStream_t stream) {
    const float* x     = (const float*)d_in[0];
    const float* w_mid = (const float*)d_in[1];
    const float* w_pt  = (const float*)d_in[2];
    const float* b_pt  = (const float*)d_in[3];
    const float* gamma = (const float*)d_in[4];
    const float* beta  = (const float*)d_in[5];
    float* y = (float*)d_out;

    __hip_bfloat16* wB2 = (__hip_bfloat16*)d_ws;
    __hip_bfloat16* xTp = (__hip_bfloat16*)((char*)d_ws + WB2_BYTES);
    float2* partials    = (float2*)((char*)d_ws + STATS_OFF);

    hipMemsetAsync(xTp, 0, XTP_BYTES, stream);                  // zero halo
    k_xpad<<<512, 256, 0, stream>>>(x, xTp);
    k_wrepack<<<(WB2_ELEMS + 255) / 256, 256, 0, stream>>>(w_mid, wB2);
    k_conv<<<1024, 512, 0, stream>>>(xTp, wB2, w_pt, b_pt, y);
    k_ystat<<<1024, 256, 0, stream>>>(y, partials);
    k_bn_apply<<<4096, 256, 0, stream>>>(y, partials, gamma, beta);
}